// Round 10
// baseline (587.883 us; speedup 1.0000x reference)
//
#include <hip/hip_runtime.h>
#include <math.h>

// VectorQuantizer: argmin_k ||x_n - c_k||^2, N=32768, K=8192, D=64, fp32.
// Round-16: r15 structure + 2 surgical fixes: (a) 2 blocks/CU (grid 512,
// RPB 1024) -> 4 waves/SIMD latency hiding; (b) conflict-free ds_write via
// splitter remap (row = tid&127, kc = tid>>7) -> each wave-write = two
// lane-linear 512B windows 8KB apart (2-way bank pairing = free, m136).
//
// r15 post-mortem: 105.8us, MfmaUtil 45% (floor 6.1k cy/body vs 15.9k wall).
// Losses identified: 5.24M bank conflicts (CH=516 stagger left 4-way write
// collisions) ~1.3k cy/body; 1 block/CU (2 w/SIMD) left dependency stalls
// uncovered -- LDS 74KB and VGPR 116 allow 2 blocks/CU, grid didn't.
// Structure (proven r15, passed absmax 0):
//  * Grid = 32 bn x 16 kb; block = 1024 rows x 512 codes; 8 waves; wave
//    holds its 64 codes' 2-plane frags in 64 VGPR (loaded once, plain).
//  * x streamed in 8 subtiles of 128 rows: raw fp32 loads (1 line/lane,
//    issued a body early) -> split2h VALU -> lane-linear ds_write. No
//    global_load_lds anywhere (path pinned at ~1.8 B/cy/wave, r7-r13).
//  * A=codes, B=x-rows; C row(reg)=code, col(lane)=x-row. Per-lane argmin
//    over 32 code-slots (ascending code, strict <), shfl_xor(32) merges
//    halves, LDS merges 8 waves, device atomicMin(u64) merges kb-blocks.
// Numerics identical to r15 (passed, absmax 0): 2-plane f16 split (plane1
// denormal-zeroed, plane2 pre-scaled 2^12), 3 products (4-chain + 8-chain),
// dist = fmaf(-2, fmaf(accB,2^-12,accA), csq), fkey u64 (negative-safe),
// lowest-code ties = numpy first-occurrence.
// C/D layout (measured m74/m101): col=lane&31, row=(reg&3)+8*(reg>>2)+4*(lane>>5).

typedef __attribute__((ext_vector_type(8)))  _Float16 h8v;
typedef __attribute__((ext_vector_type(16))) float f16v;

constexpr int NROWS = 32768;
constexpr int KC    = 8192;
constexpr int DD    = 64;
constexpr int TPB   = 512;            // 8 waves
constexpr int PTPB  = 256;            // pre/fin kernel block size
constexpr int NKB   = 16;             // code-block columns (512 codes each)
constexpr int RPB   = 1024;           // rows per block (32 row-blocks)
constexpr int SROWS = 128;            // rows per subtile
constexpr int NSUB  = RPB / SROWS;    // 8 bodies
constexpr int CH    = 512;            // chunk stride (halves; contiguous)

__device__ __forceinline__ void split2h(float v, _Float16& h1, _Float16& h2) {
  const float av = fabsf(v);
  _Float16 a = (_Float16)v;                  // RNE
  if (av < 6.1035156e-5f) a = (_Float16)0.f; // keep plane-1 out of f16 denormals
  h1 = a;
  h2 = (_Float16)((v - (float)a) * 4096.f);  // exact residual, scaled 2^12
}

// Monotone map: unsigned order of mapped bits == float order (handles negatives).
__device__ __forceinline__ unsigned fkey(float f) {
  const unsigned u = __float_as_uint(f);
  return u ^ (((unsigned)((int)u >> 31)) | 0x80000000u);
}

// Pre-kernel (128 blocks, 4 threads/code): split cb into frag-ordered groups
// (32 codes x 4096 halves; lane h*32+l = code l, k = kc*16+h*8+j), csq, and
// init gkey. Unchanged from r15 (passed).
__global__ void vq_pre_kernel(const float* __restrict__ cb,
                              _Float16* __restrict__ cbSwz,
                              float* __restrict__ csq,
                              unsigned long long* __restrict__ gkey) {
  const int gidx = blockIdx.x * PTPB + threadIdx.x;  // 0..32767
  gkey[gidx] = 0xFFFFFFFFFFFFFFFFull;                // one slot per row
  const int code = gidx >> 2;
  const int kc4  = gidx & 3;
  const float* cp = cb + (size_t)code * DD + kc4 * 16;
  float v[16];
#pragma unroll
  for (int d = 0; d < 16; d += 4) {
    const float4 g = *(const float4*)(cp + d);
    v[d] = g.x; v[d + 1] = g.y; v[d + 2] = g.z; v[d + 3] = g.w;
  }
  float s = 0.f;
#pragma unroll
  for (int d = 0; d < 16; ++d) s = fmaf(v[d], v[d], s);
  s += __shfl_xor(s, 1, 64);
  s += __shfl_xor(s, 2, 64);
  _Float16 p1[16], p2[16];
#pragma unroll
  for (int d = 0; d < 16; ++d) split2h(v[d], p1[d], p2[d]);
  const int g = code >> 5, l = code & 31;
  _Float16* base = cbSwz + (size_t)g * 4096;
#pragma unroll
  for (int p = 0; p < 2; ++p) {
    const _Float16* pl = p ? p2 : p1;
#pragma unroll
    for (int h = 0; h < 2; ++h) {
      h8v wv;
#pragma unroll
      for (int j = 0; j < 8; ++j) wv[j] = pl[h * 8 + j];
      *(h8v*)(base + (p * 4 + kc4) * 512 + (h * 32 + l) * 8) = wv;
    }
  }
  if (kc4 == 0) csq[code] = s;
}

// Split 16 raw floats (LR0..LR3) into 2 f16 planes and ds_write chunk-format.
// Thread (sr = tid&127, skc = tid>>7): within a wave, sr is lane-linear ->
// each of the 4 wave-writes is two contiguous 512B windows (conflict-free).
#define SPLITWRITE(PAR)                                                        \
  {                                                                            \
    const float ff[16] = {LR0.x, LR0.y, LR0.z, LR0.w, LR1.x, LR1.y, LR1.z,     \
                          LR1.w, LR2.x, LR2.y, LR2.z, LR2.w, LR3.x, LR3.y,     \
                          LR3.z, LR3.w};                                       \
    _Pragma("unroll")                                                          \
    for (int h = 0; h < 2; ++h) {                                              \
      h8v p1v, p2v;                                                            \
      _Pragma("unroll")                                                        \
      for (int j = 0; j < 8; ++j) {                                            \
        _Float16 a_, b_;                                                       \
        split2h(ff[h * 8 + j], a_, b_);                                        \
        p1v[j] = a_; p2v[j] = b_;                                              \
      }                                                                        \
      *(h8v*)&bufX[PAR][((sg2 * 2 + 0) * 4 + skc) * CH + (h * 32 + sr31) * 8] = p1v; \
      *(h8v*)&bufX[PAR][((sg2 * 2 + 1) * 4 + skc) * CH + (h * 32 + sr31) * 8] = p2v; \
    }                                                                          \
  }

__global__ __launch_bounds__(TPB, 4)
void vq_mfma_kernel(const float* __restrict__ x, const _Float16* __restrict__ cbSwz,
                    const float* __restrict__ csq_g,
                    unsigned long long* __restrict__ gkey) {
  __shared__ alignas(16) _Float16 bufX[2][32 * CH];           // 65536 B
  __shared__ alignas(16) unsigned long long ldsRed[8][SROWS]; // 8192 B

  const int tid  = threadIdx.x;
  const int lane = tid & 63;
  const int w    = tid >> 6;
  const int half = lane >> 5;
  const int col  = lane & 31;
  const int kb   = blockIdx.x & (NKB - 1);
  const int bn   = blockIdx.x >> 4;
  const size_t nbase = (size_t)bn * RPB;

  // ---- Persistent code fragments: 2 stripes x 2 planes x 4 kc = 64 VGPR.
  h8v cbfr[2][2][4];
#pragma unroll
  for (int q = 0; q < 2; ++q)
#pragma unroll
    for (int p = 0; p < 2; ++p)
#pragma unroll
      for (int kc = 0; kc < 4; ++kc)
        cbfr[q][p][kc] = *(const h8v*)(cbSwz +
            (size_t)(kb * 16 + w * 2 + q) * 4096 + (p * 4 + kc) * 512 + lane * 8);

  // csq for this lane's 32 code-slots (uniform per half-wave; one-time).
  const int cbase = kb * 512 + w * 64 + 4 * half;
  float csq[2][16];
#pragma unroll
  for (int q = 0; q < 2; ++q)
#pragma unroll
    for (int i = 0; i < 16; ++i)
      csq[q][i] = csq_g[cbase + q * 32 + (i & 3) + 8 * (i >> 2)];

  // Splitter task ids: thread covers (row sr, k-chunk skc) = 16 floats.
  const int sr = tid & 127, skc = tid >> 7;
  const int sg2 = sr >> 5, sr31 = sr & 31;

  // ---- Prologue: stage subtile 0 into buf 0.
  float4 LR0, LR1, LR2, LR3;
  {
    const float* xp = x + (nbase + sr) * DD + skc * 16;
    LR0 = ((const float4*)xp)[0]; LR1 = ((const float4*)xp)[1];
    LR2 = ((const float4*)xp)[2]; LR3 = ((const float4*)xp)[3];
    SPLITWRITE(0);
  }
  asm volatile("s_waitcnt lgkmcnt(0)\n\ts_barrier" ::: "memory");

  const f16v Z = {0.f,0.f,0.f,0.f,0.f,0.f,0.f,0.f,0.f,0.f,0.f,0.f,0.f,0.f,0.f,0.f};

#pragma unroll 1
  for (int t = 0; t < NSUB; ++t) {
    const int par = t & 1;
    // Issue raw loads for subtile t+1 (consumed at body bottom; far away).
    if (t + 1 < NSUB) {
      const float* xp = x + (nbase + (size_t)(t + 1) * SROWS + sr) * DD + skc * 16;
      LR0 = ((const float4*)xp)[0]; LR1 = ((const float4*)xp)[1];
      LR2 = ((const float4*)xp)[2]; LR3 = ((const float4*)xp)[3];
    }
    // 4 col-groups of 32 x-rows each.
#pragma unroll
    for (int cg = 0; cg < 4; ++cg) {
      h8v xfr[2][4];
#pragma unroll
      for (int p = 0; p < 2; ++p)
#pragma unroll
        for (int kc = 0; kc < 4; ++kc)
          xfr[p][kc] = *(const h8v*)&bufX[par][((cg * 2 + p) * 4 + kc) * CH + lane * 8];

      __builtin_amdgcn_s_setprio(1);
      f16v A0 = Z, B0 = Z, A1 = Z, B1 = Z;
#pragma unroll
      for (int kc = 0; kc < 4; ++kc) {
        A0 = __builtin_amdgcn_mfma_f32_32x32x16_f16(cbfr[0][0][kc], xfr[0][kc], A0, 0, 0, 0);
        A1 = __builtin_amdgcn_mfma_f32_32x32x16_f16(cbfr[1][0][kc], xfr[0][kc], A1, 0, 0, 0);
        B0 = __builtin_amdgcn_mfma_f32_32x32x16_f16(cbfr[0][0][kc], xfr[1][kc], B0, 0, 0, 0);
        B1 = __builtin_amdgcn_mfma_f32_32x32x16_f16(cbfr[1][0][kc], xfr[1][kc], B1, 0, 0, 0);
      }
#pragma unroll
      for (int kc = 0; kc < 4; ++kc) {
        B0 = __builtin_amdgcn_mfma_f32_32x32x16_f16(cbfr[0][1][kc], xfr[0][kc], B0, 0, 0, 0);
        B1 = __builtin_amdgcn_mfma_f32_32x32x16_f16(cbfr[1][1][kc], xfr[0][kc], B1, 0, 0, 0);
      }
      __builtin_amdgcn_s_setprio(0);

      // Per-lane argmin over its 32 code-slots (ascending code, strict <).
      float bd = INFINITY;
      unsigned bc = 0u;
#pragma unroll
      for (int i = 0; i < 16; ++i) {
        const float di = fmaf(-2.f, fmaf(B0[i], 2.44140625e-4f, A0[i]), csq[0][i]);
        if (di < bd) { bd = di; bc = (unsigned)(cbase + (i & 3) + 8 * (i >> 2)); }
      }
#pragma unroll
      for (int i = 0; i < 16; ++i) {
        const float di = fmaf(-2.f, fmaf(B1[i], 2.44140625e-4f, A1[i]), csq[1][i]);
        if (di < bd) { bd = di; bc = (unsigned)(cbase + 32 + (i & 3) + 8 * (i >> 2)); }
      }
      unsigned long long key = ((unsigned long long)fkey(bd) << 32) | bc;
      const unsigned long long o = __shfl_xor(key, 32, 64);
      if (o < key) key = o;
      if (half == 0) ldsRed[w][cg * 32 + col] = key;
    }
    // Split + write subtile t+1 into the other buffer.
    if (t + 1 < NSUB) SPLITWRITE(par ^ 1);
    asm volatile("s_waitcnt lgkmcnt(0)\n\ts_barrier" ::: "memory");
    // Merge 8 waves per row; publish via device-scope u64 atomicMin.
    if (tid < SROWS) {
      unsigned long long k0 = ldsRed[0][tid];
#pragma unroll
      for (int w2 = 1; w2 < 8; ++w2) {
        const unsigned long long o2 = ldsRed[w2][tid];
        if (o2 < k0) k0 = o2;
      }
      atomicMin(&gkey[nbase + (size_t)t * SROWS + tid], k0);
    }
    asm volatile("s_barrier" ::: "memory");
  }
}

// Final pass: key -> int32 index.
__global__ void vq_fin_kernel(const unsigned long long* __restrict__ gkey,
                              int* __restrict__ out) {
  const int n = blockIdx.x * PTPB + threadIdx.x;
  out[n] = (int)(unsigned)(gkey[n] & 0xFFFFFFFFull);
}

extern "C" void kernel_launch(void* const* d_in, const int* in_sizes, int n_in,
                              void* d_out, int out_size, void* d_ws, size_t ws_size,
                              hipStream_t stream) {
  const float* x  = (const float*)d_in[0];   // [N, 64] fp32
  const float* cb = (const float*)d_in[1];   // [K, 64] fp32
  int* out = (int*)d_out;                    // [N] int32

  // ws: cbSwz 2MB | csq 32KB | gkey 256KB  (total 2.33MB)
  _Float16* cbSwz = (_Float16*)d_ws;
  float* csq_g = (float*)((char*)d_ws + (size_t)KC * DD * 2 * 2);
  unsigned long long* gkey =
      (unsigned long long*)((char*)csq_g + (size_t)KC * 4);

  vq_pre_kernel<<<dim3(KC * 4 / PTPB), dim3(PTPB), 0, stream>>>(cb, cbSwz, csq_g, gkey);
  vq_mfma_kernel<<<dim3(NKB * (NROWS / RPB)), dim3(TPB), 0, stream>>>(
      x, cbSwz, csq_g, gkey);
  vq_fin_kernel<<<dim3(NROWS / PTPB), dim3(PTPB), 0, stream>>>(gkey, out);
}

// Round 11
// 159.555 us; speedup vs baseline: 3.6845x; 3.6845x over previous
//
#include <hip/hip_runtime.h>
#include <math.h>

// VectorQuantizer: argmin_k ||x_n - c_k||^2, N=32768, K=8192, D=64, fp32.
// Round-17: r16 with the register cap reverted -- __launch_bounds__(512,2).
//
// r16 post-mortem (541us): launch_bounds(512,4) => 64-VGPR cap for 8-wave
// blocks => full spill of cbfr/csq/argmin state (WRITE_SIZE 228MB, FETCH
// 1.24GB scratch traffic, MfmaUtil 7.8%). BUT both intended fixes verified:
// bank conflicts 5.24M -> 0 (splitter remap), occupancy 21 -> 46% (2
// blocks/CU co-resident). This round keeps grid 512 + remap and restores
// r15's (512,2) bound (compiled this structure at 116 VGPR, spill-free;
// 116 <= 128 still allows 4 waves/SIMD at runtime).
// Structure (proven r15/r16, both passed absmax 0):
//  * Grid = 32 bn x 16 kb; block = 1024 rows x 512 codes; 8 waves; wave
//    holds its 64 codes' 2-plane frags in 64 VGPR (loaded once, plain).
//  * x streamed in 8 subtiles of 128 rows: raw fp32 loads (1 line/lane,
//    issued a body early) -> split2h VALU -> lane-linear ds_write
//    (sr = tid&127: two contiguous 512B windows per wave-write, 0 conflicts).
//    No global_load_lds anywhere (path pinned ~1.8 B/cy/wave, r7-r13).
//  * A=codes, B=x-rows; C row(reg)=code, col(lane)=x-row. Per-lane argmin
//    over 32 code-slots (ascending code, strict <), shfl_xor(32) merges
//    halves, LDS merges 8 waves, device atomicMin(u64) merges kb-blocks.
// Numerics identical to r15/r16 (passed, absmax 0): 2-plane f16 split
// (plane1 denormal-zeroed, plane2 pre-scaled 2^12), 3 products (4-chain +
// 8-chain), dist = fmaf(-2, fmaf(accB,2^-12,accA), csq), fkey u64
// (negative-safe), lowest-code ties = numpy first-occurrence.
// C/D layout (measured m74/m101): col=lane&31, row=(reg&3)+8*(reg>>2)+4*(lane>>5).

typedef __attribute__((ext_vector_type(8)))  _Float16 h8v;
typedef __attribute__((ext_vector_type(16))) float f16v;

constexpr int NROWS = 32768;
constexpr int KC    = 8192;
constexpr int DD    = 64;
constexpr int TPB   = 512;            // 8 waves
constexpr int PTPB  = 256;            // pre/fin kernel block size
constexpr int NKB   = 16;             // code-block columns (512 codes each)
constexpr int RPB   = 1024;           // rows per block (32 row-blocks)
constexpr int SROWS = 128;            // rows per subtile
constexpr int NSUB  = RPB / SROWS;    // 8 bodies
constexpr int CH    = 512;            // chunk stride (halves; contiguous)

__device__ __forceinline__ void split2h(float v, _Float16& h1, _Float16& h2) {
  const float av = fabsf(v);
  _Float16 a = (_Float16)v;                  // RNE
  if (av < 6.1035156e-5f) a = (_Float16)0.f; // keep plane-1 out of f16 denormals
  h1 = a;
  h2 = (_Float16)((v - (float)a) * 4096.f);  // exact residual, scaled 2^12
}

// Monotone map: unsigned order of mapped bits == float order (handles negatives).
__device__ __forceinline__ unsigned fkey(float f) {
  const unsigned u = __float_as_uint(f);
  return u ^ (((unsigned)((int)u >> 31)) | 0x80000000u);
}

// Pre-kernel (128 blocks, 4 threads/code): split cb into frag-ordered groups
// (32 codes x 4096 halves; lane h*32+l = code l, k = kc*16+h*8+j), csq, and
// init gkey. Unchanged from r15/r16 (passed).
__global__ void vq_pre_kernel(const float* __restrict__ cb,
                              _Float16* __restrict__ cbSwz,
                              float* __restrict__ csq,
                              unsigned long long* __restrict__ gkey) {
  const int gidx = blockIdx.x * PTPB + threadIdx.x;  // 0..32767
  gkey[gidx] = 0xFFFFFFFFFFFFFFFFull;                // one slot per row
  const int code = gidx >> 2;
  const int kc4  = gidx & 3;
  const float* cp = cb + (size_t)code * DD + kc4 * 16;
  float v[16];
#pragma unroll
  for (int d = 0; d < 16; d += 4) {
    const float4 g = *(const float4*)(cp + d);
    v[d] = g.x; v[d + 1] = g.y; v[d + 2] = g.z; v[d + 3] = g.w;
  }
  float s = 0.f;
#pragma unroll
  for (int d = 0; d < 16; ++d) s = fmaf(v[d], v[d], s);
  s += __shfl_xor(s, 1, 64);
  s += __shfl_xor(s, 2, 64);
  _Float16 p1[16], p2[16];
#pragma unroll
  for (int d = 0; d < 16; ++d) split2h(v[d], p1[d], p2[d]);
  const int g = code >> 5, l = code & 31;
  _Float16* base = cbSwz + (size_t)g * 4096;
#pragma unroll
  for (int p = 0; p < 2; ++p) {
    const _Float16* pl = p ? p2 : p1;
#pragma unroll
    for (int h = 0; h < 2; ++h) {
      h8v wv;
#pragma unroll
      for (int j = 0; j < 8; ++j) wv[j] = pl[h * 8 + j];
      *(h8v*)(base + (p * 4 + kc4) * 512 + (h * 32 + l) * 8) = wv;
    }
  }
  if (kc4 == 0) csq[code] = s;
}

// Split 16 raw floats (LR0..LR3) into 2 f16 planes and ds_write chunk-format.
// Thread (sr = tid&127, skc = tid>>7): within a wave, sr is lane-linear ->
// each of the 4 wave-writes is two contiguous 512B windows (conflict-free;
// verified r16: SQ_LDS_BANK_CONFLICT = 0).
#define SPLITWRITE(PAR)                                                        \
  {                                                                            \
    const float ff[16] = {LR0.x, LR0.y, LR0.z, LR0.w, LR1.x, LR1.y, LR1.z,     \
                          LR1.w, LR2.x, LR2.y, LR2.z, LR2.w, LR3.x, LR3.y,     \
                          LR3.z, LR3.w};                                       \
    _Pragma("unroll")                                                          \
    for (int h = 0; h < 2; ++h) {                                              \
      h8v p1v, p2v;                                                            \
      _Pragma("unroll")                                                        \
      for (int j = 0; j < 8; ++j) {                                            \
        _Float16 a_, b_;                                                       \
        split2h(ff[h * 8 + j], a_, b_);                                        \
        p1v[j] = a_; p2v[j] = b_;                                              \
      }                                                                        \
      *(h8v*)&bufX[PAR][((sg2 * 2 + 0) * 4 + skc) * CH + (h * 32 + sr31) * 8] = p1v; \
      *(h8v*)&bufX[PAR][((sg2 * 2 + 1) * 4 + skc) * CH + (h * 32 + sr31) * 8] = p2v; \
    }                                                                          \
  }

__global__ __launch_bounds__(TPB, 2)
void vq_mfma_kernel(const float* __restrict__ x, const _Float16* __restrict__ cbSwz,
                    const float* __restrict__ csq_g,
                    unsigned long long* __restrict__ gkey) {
  __shared__ alignas(16) _Float16 bufX[2][32 * CH];           // 65536 B
  __shared__ alignas(16) unsigned long long ldsRed[8][SROWS]; // 8192 B

  const int tid  = threadIdx.x;
  const int lane = tid & 63;
  const int w    = tid >> 6;
  const int half = lane >> 5;
  const int col  = lane & 31;
  const int kb   = blockIdx.x & (NKB - 1);
  const int bn   = blockIdx.x >> 4;
  const size_t nbase = (size_t)bn * RPB;

  // ---- Persistent code fragments: 2 stripes x 2 planes x 4 kc = 64 VGPR.
  h8v cbfr[2][2][4];
#pragma unroll
  for (int q = 0; q < 2; ++q)
#pragma unroll
    for (int p = 0; p < 2; ++p)
#pragma unroll
      for (int kc = 0; kc < 4; ++kc)
        cbfr[q][p][kc] = *(const h8v*)(cbSwz +
            (size_t)(kb * 16 + w * 2 + q) * 4096 + (p * 4 + kc) * 512 + lane * 8);

  // csq for this lane's 32 code-slots (uniform per half-wave; one-time).
  const int cbase = kb * 512 + w * 64 + 4 * half;
  float csq[2][16];
#pragma unroll
  for (int q = 0; q < 2; ++q)
#pragma unroll
    for (int i = 0; i < 16; ++i)
      csq[q][i] = csq_g[cbase + q * 32 + (i & 3) + 8 * (i >> 2)];

  // Splitter task ids: thread covers (row sr, k-chunk skc) = 16 floats.
  const int sr = tid & 127, skc = tid >> 7;
  const int sg2 = sr >> 5, sr31 = sr & 31;

  // ---- Prologue: stage subtile 0 into buf 0.
  float4 LR0, LR1, LR2, LR3;
  {
    const float* xp = x + (nbase + sr) * DD + skc * 16;
    LR0 = ((const float4*)xp)[0]; LR1 = ((const float4*)xp)[1];
    LR2 = ((const float4*)xp)[2]; LR3 = ((const float4*)xp)[3];
    SPLITWRITE(0);
  }
  asm volatile("s_waitcnt lgkmcnt(0)\n\ts_barrier" ::: "memory");

  const f16v Z = {0.f,0.f,0.f,0.f,0.f,0.f,0.f,0.f,0.f,0.f,0.f,0.f,0.f,0.f,0.f,0.f};

#pragma unroll 1
  for (int t = 0; t < NSUB; ++t) {
    const int par = t & 1;
    // Issue raw loads for subtile t+1 (consumed at body bottom; far away).
    if (t + 1 < NSUB) {
      const float* xp = x + (nbase + (size_t)(t + 1) * SROWS + sr) * DD + skc * 16;
      LR0 = ((const float4*)xp)[0]; LR1 = ((const float4*)xp)[1];
      LR2 = ((const float4*)xp)[2]; LR3 = ((const float4*)xp)[3];
    }
    // 4 col-groups of 32 x-rows each.
#pragma unroll
    for (int cg = 0; cg < 4; ++cg) {
      h8v xfr[2][4];
#pragma unroll
      for (int p = 0; p < 2; ++p)
#pragma unroll
        for (int kc = 0; kc < 4; ++kc)
          xfr[p][kc] = *(const h8v*)&bufX[par][((cg * 2 + p) * 4 + kc) * CH + lane * 8];

      __builtin_amdgcn_s_setprio(1);
      f16v A0 = Z, B0 = Z, A1 = Z, B1 = Z;
#pragma unroll
      for (int kc = 0; kc < 4; ++kc) {
        A0 = __builtin_amdgcn_mfma_f32_32x32x16_f16(cbfr[0][0][kc], xfr[0][kc], A0, 0, 0, 0);
        A1 = __builtin_amdgcn_mfma_f32_32x32x16_f16(cbfr[1][0][kc], xfr[0][kc], A1, 0, 0, 0);
        B0 = __builtin_amdgcn_mfma_f32_32x32x16_f16(cbfr[0][0][kc], xfr[1][kc], B0, 0, 0, 0);
        B1 = __builtin_amdgcn_mfma_f32_32x32x16_f16(cbfr[1][0][kc], xfr[1][kc], B1, 0, 0, 0);
      }
#pragma unroll
      for (int kc = 0; kc < 4; ++kc) {
        B0 = __builtin_amdgcn_mfma_f32_32x32x16_f16(cbfr[0][1][kc], xfr[0][kc], B0, 0, 0, 0);
        B1 = __builtin_amdgcn_mfma_f32_32x32x16_f16(cbfr[1][1][kc], xfr[0][kc], B1, 0, 0, 0);
      }
      __builtin_amdgcn_s_setprio(0);

      // Per-lane argmin over its 32 code-slots (ascending code, strict <).
      float bd = INFINITY;
      unsigned bc = 0u;
#pragma unroll
      for (int i = 0; i < 16; ++i) {
        const float di = fmaf(-2.f, fmaf(B0[i], 2.44140625e-4f, A0[i]), csq[0][i]);
        if (di < bd) { bd = di; bc = (unsigned)(cbase + (i & 3) + 8 * (i >> 2)); }
      }
#pragma unroll
      for (int i = 0; i < 16; ++i) {
        const float di = fmaf(-2.f, fmaf(B1[i], 2.44140625e-4f, A1[i]), csq[1][i]);
        if (di < bd) { bd = di; bc = (unsigned)(cbase + 32 + (i & 3) + 8 * (i >> 2)); }
      }
      unsigned long long key = ((unsigned long long)fkey(bd) << 32) | bc;
      const unsigned long long o = __shfl_xor(key, 32, 64);
      if (o < key) key = o;
      if (half == 0) ldsRed[w][cg * 32 + col] = key;
    }
    // Split + write subtile t+1 into the other buffer.
    if (t + 1 < NSUB) SPLITWRITE(par ^ 1);
    asm volatile("s_waitcnt lgkmcnt(0)\n\ts_barrier" ::: "memory");
    // Merge 8 waves per row; publish via device-scope u64 atomicMin.
    if (tid < SROWS) {
      unsigned long long k0 = ldsRed[0][tid];
#pragma unroll
      for (int w2 = 1; w2 < 8; ++w2) {
        const unsigned long long o2 = ldsRed[w2][tid];
        if (o2 < k0) k0 = o2;
      }
      atomicMin(&gkey[nbase + (size_t)t * SROWS + tid], k0);
    }
    asm volatile("s_barrier" ::: "memory");
  }
}

// Final pass: key -> int32 index.
__global__ void vq_fin_kernel(const unsigned long long* __restrict__ gkey,
                              int* __restrict__ out) {
  const int n = blockIdx.x * PTPB + threadIdx.x;
  out[n] = (int)(unsigned)(gkey[n] & 0xFFFFFFFFull);
}

extern "C" void kernel_launch(void* const* d_in, const int* in_sizes, int n_in,
                              void* d_out, int out_size, void* d_ws, size_t ws_size,
                              hipStream_t stream) {
  const float* x  = (const float*)d_in[0];   // [N, 64] fp32
  const float* cb = (const float*)d_in[1];   // [K, 64] fp32
  int* out = (int*)d_out;                    // [N] int32

  // ws: cbSwz 2MB | csq 32KB | gkey 256KB  (total 2.33MB)
  _Float16* cbSwz = (_Float16*)d_ws;
  float* csq_g = (float*)((char*)d_ws + (size_t)KC * DD * 2 * 2);
  unsigned long long* gkey =
      (unsigned long long*)((char*)csq_g + (size_t)KC * 4);

  vq_pre_kernel<<<dim3(KC * 4 / PTPB), dim3(PTPB), 0, stream>>>(cb, cbSwz, csq_g, gkey);
  vq_mfma_kernel<<<dim3(NKB * (NROWS / RPB)), dim3(TPB), 0, stream>>>(
      x, cbSwz, csq_g, gkey);
  vq_fin_kernel<<<dim3(NROWS / PTPB), dim3(PTPB), 0, stream>>>(gkey, out);
}